// Round 13
// baseline (315.155 us; speedup 1.0000x reference)
//
#include <hip/hip_runtime.h>

// BatchAdaptiveConv2d via implicit GEMM on bf16 MFMA.
// out[b,o,y,x] = sum_{i,dy,dx} x[b,i,y+dy-1,x+dx-1] * W[i,o,dy,dx]*wadapt[b,i]
//               + bias[o]*badapt[b,o]
// R15 = R14 resubmitted (GPUAcquisitionTimeout; never benched).
// R14: BARRIER-FREE main loop (convoy-breaker).
//  Falsified: occupancy(R5), VMEM rate(R9), traffic(R10), store order(R11),
//  DRAM granule(R12), prefetch depth(R13). Invariant across all: barrier-paced
//  lockstep — all waves convoy through stage/compute phases, so every iter
//  costs the congested chip-wide load-tail latency (~12.5us vs ~1us of work).
//  Fix: wave w owns contiguous rows 8w..8w+7; wave-PRIVATE 3-slot rolling LDS
//  window; 1 row staged per iter with 1-iter register lookahead (La/Lb);
//  zero barriers after weight staging. Compute/store/swizzle byte-identical
//  to R10. 8 fully independent waves/CU overlap load latency via TLP.

#define B_    16
#define CIN   32
#define COUT  32
#define H_    256
#define W_    256
#define EMB2  512

#define XPX   66               // 64 + 2 halo pixels per LDS row
#define PXS   32               // ushorts per pixel (32 ch * bf16)
#define ROWS_ (XPX*PXS)        // 2112 ushorts per row-slot
#define WSLOT 3                // private slots per wave

using short8  = __attribute__((ext_vector_type(8))) short;
using float4v = __attribute__((ext_vector_type(4))) float;
using float4r = __attribute__((ext_vector_type(4))) float;

__device__ __forceinline__ unsigned short f2bf(float f) {
    unsigned u = __builtin_bit_cast(unsigned, f);
    u += 0x7FFFu + ((u >> 16) & 1u);      // RNE
    return (unsigned short)(u >> 16);
}
__device__ __forceinline__ unsigned pk2(float a, float b) {
    return (unsigned)f2bf(a) | ((unsigned)f2bf(b) << 16);
}

// ---------------- kernel 1: adapt coefficients ----------------
// ws[0..511] = wadapt[b][i]; ws[512..1023] = bias[o]*badapt[b][o]
__global__ __launch_bounds__(256) void adapt_kernel(
    const float* __restrict__ cond, const float* __restrict__ lpe,
    const float* __restrict__ wa_w, const float* __restrict__ wa_b,
    const float* __restrict__ ba_w, const float* __restrict__ ba_b,
    const float* __restrict__ bias, float* __restrict__ ws)
{
    __shared__ float iv[EMB2];
    __shared__ float partial[64][4];
    const int b = blockIdx.x;
    const int t = threadIdx.x;

    iv[t]       = cond[b*256 + t];
    iv[t + 256] = lpe[b*256 + t];
    __syncthreads();

    const int out  = t & 63;
    const int part = t >> 6;
    const float* row = (out < 32) ? (wa_w + out*EMB2) : (ba_w + (out-32)*EMB2);
    float s = 0.f;
    #pragma unroll 8
    for (int j = part*128; j < part*128 + 128; ++j) s += iv[j] * row[j];
    partial[out][part] = s;
    __syncthreads();

    if (t < 64) {
        float v = partial[t][0] + partial[t][1] + partial[t][2] + partial[t][3];
        if (t < 32) ws[b*32 + t] = v + wa_b[t];
        else {
            int o = t - 32;
            ws[512 + b*32 + o] = bias[o] * (v + ba_b[o]);
        }
    }
}

// ---------------- kernel 2: MFMA conv ----------------
// grid (W/64, H/32, B); block 256 = 4 waves. Wave w owns rows 8w..8w+7.
__global__ __launch_bounds__(256, 2) void conv_kernel(
    const float* __restrict__ x, const float* __restrict__ weights,
    const float* __restrict__ ws, float* __restrict__ out)
{
    __shared__ __align__(16) unsigned short xbuf[4 * WSLOT * ROWS_]; // 50688 B
    __shared__ __align__(16) unsigned short wbuf[9 * 2 * 64 * 8];    // 18432 B

    const int tid    = threadIdx.x;
    const int lane   = tid & 63;
    const int w      = tid >> 6;        // wave 0..3
    const int ln15   = lane & 15;
    const int kg     = lane >> 4;       // k-group 0..3
    const int xstrip = blockIdx.x * 64;
    const int ystrip = blockIdx.y * 32;
    const int b      = blockIdx.z;

    // ---- scaled weights -> wbuf[tap][ot][lane][j]: lane-consecutive 16B,
    //      conflict-free ds_read_b128 per (tap,ot). (cooperative, 1 barrier)
    for (int idx = tid; idx < CIN*COUT*9; idx += 256) {
        int i   = idx / 288;
        int rem = idx - i*288;
        int o   = rem / 9;
        int tap = rem - o*9;
        float v = weights[idx] * ws[b*32 + i];
        wbuf[((tap*2 + (o>>4))*64 + ((i>>3)*16 + (o&15)))*8 + (i&7)] = f2bf(v);
    }

    // ---- per-wave staging helpers (wave-private LDS region) ----
    const int q = lane & 15;            // staging chunk column (4 px)
    const int g = lane >> 4;            // staging channel group

    // main: this lane loads 8 ch x 4 px of row gy (8x dwordx4)
    auto ld_main = [&](int gy, float4r (&L)[8]) {
        if ((unsigned)gy < 256u) {
            const float* src = x + (((size_t)(b*CIN + g*8) << 16) + (gy << 8)
                                    + (xstrip + 4*q));
            #pragma unroll
            for (int j = 0; j < 8; ++j)
                L[j] = *(const float4r*)&src[(size_t)j << 16];
        } else {
            #pragma unroll
            for (int j = 0; j < 8; ++j) L[j] = float4r{0.f, 0.f, 0.f, 0.f};
        }
    };
    // write row j (local index, -1..32) into private slot (j+1)%3
    auto wr_main = [&](int j, const float4r (&L)[8]) {
        unsigned slot = (unsigned)(j + 1) % 3u;
        unsigned base = (w*WSLOT + slot) * ROWS_;
        #pragma unroll
        for (int n = 0; n < 4; ++n) {
            int k = (n + q) & 3;
            int p = 4*q + k + 1;                 // LDS pixel index 1..64
            uint4 pk;
            pk.x = pk2(L[0][k], L[1][k]);
            pk.y = pk2(L[2][k], L[3][k]);
            pk.z = pk2(L[4][k], L[5][k]);
            pk.w = pk2(L[6][k], L[7][k]);
            *(uint4*)&xbuf[base + p*PXS + ((g ^ ((p >> 1) & 3)) * 8)] = pk;
        }
    };
    // halo: lanes 0..7 handle (side, ch-group); 8 scalar loads each
    auto ld_halo = [&](int gy, float (&f)[8]) {
        int side = lane & 1, hg = (lane >> 1) & 3;
        int xx = xstrip + (side ? 64 : -1);
        if (((unsigned)gy < 256u) & ((unsigned)xx < 256u)) {
            const float* src = x + (((size_t)(b*CIN + hg*8) << 16) + (gy << 8) + xx);
            #pragma unroll
            for (int j = 0; j < 8; ++j) f[j] = src[(size_t)j << 16];
        } else {
            #pragma unroll
            for (int j = 0; j < 8; ++j) f[j] = 0.f;
        }
    };
    auto wr_halo = [&](int j, const float (&f)[8]) {
        int side = lane & 1, hg = (lane >> 1) & 3;
        int p = side ? 65 : 0;
        unsigned slot = (unsigned)(j + 1) % 3u;
        unsigned base = (w*WSLOT + slot) * ROWS_;
        uint4 pk;
        pk.x = pk2(f[0], f[1]); pk.y = pk2(f[2], f[3]);
        pk.z = pk2(f[4], f[5]); pk.w = pk2(f[6], f[7]);
        *(uint4*)&xbuf[base + p*PXS + ((hg ^ ((p >> 1) & 3)) * 8)] = pk;
    };

    // ---- per-lane modulated bias (out = ot*16 + kg*4 + r) ----
    float bm[2][4];
    #pragma unroll
    for (int ot = 0; ot < 2; ++ot)
        #pragma unroll
        for (int r = 0; r < 4; ++r)
            bm[ot][r] = ws[512 + b*32 + ot*16 + kg*4 + r];

    __syncthreads();            // wbuf ready — LAST barrier in the kernel

    // ---- prologue: direct-stage rows 8w-1, 8w (serial; prologue only) ----
    float4r La[8], Lb[8];
    float   PHa[8], PHb[8];
    {
        ld_main(ystrip + 8*w - 1, La);
        if (lane < 8) ld_halo(ystrip + 8*w - 1, PHa);
        wr_main(8*w - 1, La);
        if (lane < 8) wr_halo(8*w - 1, PHa);
        ld_main(ystrip + 8*w, La);
        if (lane < 8) ld_halo(ystrip + 8*w, PHa);
        wr_main(8*w, La);
        if (lane < 8) wr_halo(8*w, PHa);
    }
    // issue row 8w+1 async (consumed at r=0)
    ld_main(ystrip + 8*w + 1, La);
    if (lane < 8) ld_halo(ystrip + 8*w + 1, PHa);

    // ---- one iteration: stage row orow+1 (from regs), issue row orow+2,
    //      compute output row orow, store. No barriers — wave-local only. ----
    auto conv_iter = [&](int r, float4r (&LC)[8], float (&PHc)[8],
                         float4r (&LN)[8], float (&PHn)[8], bool issue) {
        const int orow = 8*w + r;           // local output row
        const int gy   = ystrip + orow;

        // WAR guard: prior iter's slot reads complete (wave-local wait)
        asm volatile("s_waitcnt lgkmcnt(0)" ::: "memory");
        wr_main(orow + 1, LC);              // vmcnt wait on LC only (arrived)
        if (lane < 8) wr_halo(orow + 1, PHc);
        if (issue) {
            ld_main(ystrip + orow + 2, LN); // fire next row's loads NOW
            if (lane < 8) ld_halo(ystrip + orow + 2, PHn);
        }
        // writes visible to own reads before compute
        asm volatile("s_waitcnt lgkmcnt(0)" ::: "memory");
        asm volatile("" ::: "memory");

        float4v acc[4][2];
        #pragma unroll
        for (int c = 0; c < 4; ++c) {
            acc[c][0] = float4v{0.f, 0.f, 0.f, 0.f};
            acc[c][1] = float4v{0.f, 0.f, 0.f, 0.f};
        }

        #pragma unroll
        for (int dy = 0; dy < 3; ++dy) {
            // row orow+dy-1 lives in private slot (orow+dy)%3
            int s3 = (orow + dy) % 3;
            const int rowbase = (w*WSLOT + s3) * ROWS_;
            #pragma unroll
            for (int dx = 0; dx < 3; ++dx) {
                const int tap = dy*3 + dx;
                short8 a0 = *(const short8*)&wbuf[((tap*2 + 0)*64 + lane)*8];
                short8 a1 = *(const short8*)&wbuf[((tap*2 + 1)*64 + lane)*8];
                #pragma unroll
                for (int c = 0; c < 4; ++c) {
                    int p = c*16 + dx + ln15;           // LDS pixel index
                    int a = rowbase + p*PXS + ((kg ^ ((p >> 1) & 3)) * 8);
                    short8 xf = *(const short8*)&xbuf[a];
                    acc[c][0] = __builtin_amdgcn_mfma_f32_16x16x32_bf16(
                                    a0, xf, acc[c][0], 0, 0, 0);
                    acc[c][1] = __builtin_amdgcn_mfma_f32_16x16x32_bf16(
                                    a1, xf, acc[c][1], 0, 0, 0);
                }
            }
        }

        // stores: D row(out) = kg*4 + r2, col(pixel) = ln15 (same as R10)
        #pragma unroll
        for (int c = 0; c < 4; ++c) {
            const int xcol = xstrip + c*16 + ln15;
            #pragma unroll
            for (int ot = 0; ot < 2; ++ot) {
                const int obase = ot*16 + kg*4;
                #pragma unroll
                for (int r2 = 0; r2 < 4; ++r2) {
                    out[((size_t)(b*COUT + obase + r2)*256 + gy)*256 + xcol] =
                        acc[c][ot][r2] + bm[ot][r2];
                }
            }
        }
    };

    for (int rr = 0; rr < 4; ++rr) {
        conv_iter(2*rr,     La, PHa, Lb, PHb, true);
        conv_iter(2*rr + 1, Lb, PHb, La, PHa, rr < 3);
    }
}

extern "C" void kernel_launch(void* const* d_in, const int* in_sizes, int n_in,
                              void* d_out, int out_size, void* d_ws, size_t ws_size,
                              hipStream_t stream) {
    const float* x       = (const float*)d_in[0];
    const float* cond    = (const float*)d_in[1];
    const float* lpe     = (const float*)d_in[2];
    const float* weights = (const float*)d_in[3];
    const float* bias    = (const float*)d_in[4];
    const float* wa_w    = (const float*)d_in[5];
    const float* wa_b    = (const float*)d_in[6];
    const float* ba_w    = (const float*)d_in[7];
    const float* ba_b    = (const float*)d_in[8];
    float* outp = (float*)d_out;
    float* ws   = (float*)d_ws;    // 1024 floats: wadapt | bias*badapt

    adapt_kernel<<<dim3(B_), dim3(256), 0, stream>>>(
        cond, lpe, wa_w, wa_b, ba_w, ba_b, bias, ws);

    conv_kernel<<<dim3(W_/64, H_/32, B_), dim3(256), 0, stream>>>(
        x, weights, ws, outp);
}